// Round 3
// baseline (234.970 us; speedup 1.0000x reference)
//
#include <hip/hip_runtime.h>

// Multinomial via sum tree, single fused kernel + software grid barrier.
// CAP=2^21 leaves, NSAMP=2^20 stratified samples, 21 traversal steps.
// ws tree holds internal levels 10..18 (slots 1023..524286 of root-first
// layout). Levels 19,20 + leaf compare are done in-register from one 32 B
// prio load; levels 0..12 are rebuilt/staged per-block in LDS (exact
// pairwise sums -> bit-identical to reference).
//
// Grid barrier safety: 1024 blocks x 256 thr, 32764 B LDS -> 5 blocks/CU
// capacity (160 KiB LDS), so all 1024 blocks are co-resident on 256 CUs
// and the spin barrier cannot deadlock. Cross-XCD visibility: agent-scope
// atomics + __threadfence (L2 writeback/invalidate on gfx9xx).

#define CAP    (1 << 21)
#define NSAMP  (1 << 20)
#define L18OFF ((1 << 18) - 1)   // 262143
#define NBLK   1024

__global__ __launch_bounds__(256) void fused_kernel(const float* __restrict__ prio,
                                                    const float* __restrict__ uniform,
                                                    float* __restrict__ tree,
                                                    unsigned int* __restrict__ bar,
                                                    int* __restrict__ out) {
    __shared__ __align__(16) float nds[8191];   // 32764 B
    const int b = blockIdx.x, t = threadIdx.x;

    // ---- Phase 1: block b reduces leaves [2048b, 2048(b+1)) to levels 18..10
    {
        const float4* p4 = (const float4*)(prio + (size_t)b * 2048);
        float4 x = p4[2 * t], y = p4[2 * t + 1];
        float n18 = ((x.x + x.y) + (x.z + x.w)) + ((y.x + y.y) + (y.z + y.w));
        tree[L18OFF + b * 256 + t] = n18;       // level 18, coalesced
        nds[t] = n18;
        __syncthreads();
        float* src = nds;                       // ping-pong regions in LDS
        float* dst = nds + 4096;
        int cnt = 128, off = (1 << 17) - 1;
        for (int lvl = 17; lvl >= 10; --lvl) {
            if (t < cnt) {
                float r = src[2 * t] + src[2 * t + 1];
                dst[t] = r;
                tree[off + b * cnt + t] = r;
            }
            __syncthreads();
            float* tmp = src; src = dst; dst = tmp;
            off = (off - 1) >> 1;
            cnt >>= 1;
        }
    }

    // ---- Grid barrier (all 1024 blocks co-resident; see header comment)
    __threadfence();                            // release: make tree visible
    if (t == 0) {
        __hip_atomic_fetch_add(bar, 1u, __ATOMIC_ACQ_REL, __HIP_MEMORY_SCOPE_AGENT);
        while (__hip_atomic_load(bar, __ATOMIC_ACQUIRE, __HIP_MEMORY_SCOPE_AGENT) < NBLK) {
            __builtin_amdgcn_s_sleep(8);
        }
    }
    __syncthreads();
    __threadfence();                            // acquire: invalidate stale cache

    // ---- Phase 2a: stage levels 10..12, rebuild 9..0 in LDS
    for (int i = 1023 + t; i < 8191; i += 256) nds[i] = tree[i];
    __syncthreads();
    {
        int cnt = 512, off = 511;
        for (int lvl = 9; lvl >= 0; --lvl) {
            for (int i = t; i < cnt; i += 256) {
                int n = off + i;
                nds[n] = nds[2 * n + 1] + nds[2 * n + 2];
            }
            __syncthreads();
            off = (off - 1) >> 1;
            cnt >>= 1;
        }
    }

    // ---- Phase 2b: 4 samples per thread, 4 interleaved chains for ILP
    const float total = nds[0];
    const float scale = total / (float)NSAMP;   // exact pow-2 divide
    const int base = b * 1024 + t;

    float s[4];
    int   id[4];
    #pragma unroll
    for (int q = 0; q < 4; ++q) {
        int j = base + 256 * q;
        s[q]  = uniform[j] * total / (float)NSAMP + scale * (float)j;  // == ref
        id[q] = 0;
    }
    #pragma unroll
    for (int d = 0; d < 12; ++d) {              // levels 1..12 from LDS
        #pragma unroll
        for (int q = 0; q < 4; ++q) {
            int left = 2 * id[q] + 1;
            float lv = nds[left];
            bool r = s[q] > lv;                 // ref: go_left = s <= lv
            s[q]  = r ? s[q] - lv : s[q];
            id[q] = r ? left + 1 : left;
        }
    }
    #pragma unroll
    for (int d = 0; d < 6; ++d) {               // levels 13..18 from global
        #pragma unroll
        for (int q = 0; q < 4; ++q) {
            int left = 2 * id[q] + 1;
            float lv = tree[left];
            bool r = s[q] > lv;
            s[q]  = r ? s[q] - lv : s[q];
            id[q] = r ? left + 1 : left;
        }
    }
    #pragma unroll
    for (int q = 0; q < 4; ++q) {               // levels 19,20 + leaf in-register
        int p = id[q] - L18OFF;
        const float4* pp = (const float4*)prio + 2 * (size_t)p;
        float4 x = pp[0], y = pp[1];            // leaves 8p..8p+7
        float l19 = (x.x + x.y) + (x.z + x.w);
        bool r1 = s[q] > l19;
        float ss = r1 ? s[q] - l19 : s[q];
        float l20 = r1 ? (y.x + y.y) : (x.x + x.y);
        bool r2 = ss > l20;
        ss = r2 ? ss - l20 : ss;
        float leaf = r1 ? (r2 ? y.z : y.x) : (r2 ? x.z : x.x);
        bool r3 = ss > leaf;
        out[base + 256 * q] = 8 * p + (r1 ? 4 : 0) + (r2 ? 2 : 0) + (r3 ? 1 : 0);
    }
}

extern "C" void kernel_launch(void* const* d_in, const int* in_sizes, int n_in,
                              void* d_out, int out_size, void* d_ws, size_t ws_size,
                              hipStream_t stream) {
    const float* prio    = (const float*)d_in[0];   // [CAP]
    const float* uniform = (const float*)d_in[1];   // [NSAMP]
    (void)in_sizes; (void)n_in; (void)out_size; (void)ws_size;

    float* tree = (float*)d_ws;                       // slots 0..524286 used
    unsigned int* bar = (unsigned int*)((float*)d_ws + (1 << 20));  // past tree

    hipMemsetAsync(bar, 0, 4, stream);                // reset barrier counter
    fused_kernel<<<NBLK, 256, 0, stream>>>(prio, uniform, tree, bar, (int*)d_out);
}

// Round 4
// 76.557 us; speedup vs baseline: 3.0692x; 3.0692x over previous
//
#include <hip/hip_runtime.h>

// Multinomial via sum tree, two kernels (grid barrier measured at ~150us on
// 8-XCD MI355X -- cross-XCD fence tax -- so two launches is cheaper).
//
// CAP=2^21 leaves, NSAMP=2^20 stratified samples, 21 traversal steps.
// Storage:
//   tree    (ws, slots 1023..8190): standard root-first layout, levels 10..12
//           only -- staged to LDS by the sample kernel, which rebuilds 9..0.
//   blocked (ws+32KB): levels 13..18 as 4096 records of 128 floats, one per
//           level-12 node. Mini-heap within a record: level-13 pair at r[0..1],
//           children of local k at r[2k+2], r[2k+3]. All 6 remaining hops hit
//           one 512 B record -> 1 L2 fetch + L1 hits instead of 6 L2 hops.
//   levels 19,20 + leaf compare: in-register from one 32 B prio load.
// All sums use the reference's exact pairwise association -> absmax 0.

#define CAP    (1 << 21)
#define NSAMP  (1 << 20)

// ---- Build: 512 blocks x 256 threads; block owns 4096 leaves -------------
__global__ __launch_bounds__(256) void build_tree(const float* __restrict__ prio,
                                                  float* __restrict__ tree,
                                                  float* __restrict__ blocked) {
    __shared__ float L18[512], L17[256], L16[128], L15[64], L14[32],
                     L13[16],  L12[8],   L11[4],   L10[2];
    __shared__ __align__(16) float rec[1024];
    const int b = blockIdx.x, t = threadIdx.x;

    // 16 leaves/thread -> two level-18 nodes (8-leaf sums, ref association)
    {
        const float4* p4 = (const float4*)(prio + (size_t)b * 4096);
        float4 x0 = p4[4*t+0], x1 = p4[4*t+1], x2 = p4[4*t+2], x3 = p4[4*t+3];
        L18[2*t]   = ((x0.x+x0.y)+(x0.z+x0.w)) + ((x1.x+x1.y)+(x1.z+x1.w));
        L18[2*t+1] = ((x2.x+x2.y)+(x2.z+x2.w)) + ((x3.x+x3.y)+(x3.z+x3.w));
    }
    __syncthreads();
    L17[t] = L18[2*t] + L18[2*t+1];              __syncthreads();
    if (t < 128) L16[t] = L17[2*t] + L17[2*t+1]; __syncthreads();
    if (t <  64) L15[t] = L16[2*t] + L16[2*t+1]; __syncthreads();
    if (t <  32) L14[t] = L15[2*t] + L15[2*t+1]; __syncthreads();
    if (t <  16) L13[t] = L14[2*t] + L14[2*t+1]; __syncthreads();
    if (t <   8) L12[t] = L13[2*t] + L13[2*t+1]; __syncthreads();
    if (t <   4) L11[t] = L12[2*t] + L12[2*t+1]; __syncthreads();
    if (t <   2) L10[t] = L11[2*t] + L11[2*t+1]; __syncthreads();

    // standard layout, levels 12..10 (sample kernel stages these)
    if (t < 8) tree[4095 + b*8 + t] = L12[t];
    if (t < 4) tree[2047 + b*4 + t] = L11[t];
    if (t < 2) tree[1023 + b*2 + t] = L10[t];

    // blocked records: 8 level-12 subtrees per block, 128 floats each
    for (int i = t; i < 1024; i += 256) {
        int r = i >> 7, off = i & 127;
        float v = 0.0f;
        if      (off <   2) v = L13[ 2*r + off];
        else if (off <   6) v = L14[ 4*r + off -  2];
        else if (off <  14) v = L15[ 8*r + off -  6];
        else if (off <  30) v = L16[16*r + off - 14];
        else if (off <  62) v = L17[32*r + off - 30];
        else if (off < 126) v = L18[64*r + off - 62];
        rec[i] = v;
    }
    __syncthreads();
    ((float4*)(blocked + (size_t)b * 1024))[t] = ((const float4*)rec)[t];  // coalesced 16B
}

// ---- Sample: 1024 blocks x 256 threads x 4 chains/thread ------------------
__global__ __launch_bounds__(256) void sample_kernel(const float* __restrict__ tree,
                                                     const float* __restrict__ blocked,
                                                     const float* __restrict__ prio,
                                                     const float* __restrict__ uniform,
                                                     int* __restrict__ out) {
    __shared__ float nds[8191];                 // levels 0..12, 32 KB
    const int t = threadIdx.x;

    for (int i = 1023 + t; i < 8191; i += 256) nds[i] = tree[i];  // levels 10..12
    __syncthreads();
    {
        int cnt = 512, off = 511;               // rebuild levels 9..0 (exact sums)
        for (int lvl = 9; lvl >= 0; --lvl) {
            for (int i = t; i < cnt; i += 256) {
                int n = off + i;
                nds[n] = nds[2*n+1] + nds[2*n+2];
            }
            __syncthreads();
            off = (off - 1) >> 1;
            cnt >>= 1;
        }
    }

    const float total = nds[0];
    const float scale = total / (float)NSAMP;   // exact pow-2 divide
    const int base = blockIdx.x * 1024 + t;

    float s[4]; int id[4];
    #pragma unroll
    for (int q = 0; q < 4; ++q) {
        int j = base + 256 * q;
        s[q]  = uniform[j] * total / (float)NSAMP + scale * (float)j;  // == ref
        id[q] = 0;
    }

    #pragma unroll
    for (int d = 0; d < 12; ++d) {              // levels 1..12 from LDS
        #pragma unroll
        for (int q = 0; q < 4; ++q) {
            int left = 2 * id[q] + 1;
            float lv = nds[left];
            bool r = s[q] > lv;                 // ref: go_left = s <= lv
            s[q]  = r ? s[q] - lv : s[q];
            id[q] = r ? left + 1 : left;
        }
    }

    int p12[4], k[4];
    #pragma unroll
    for (int q = 0; q < 4; ++q) {               // level 13: record root pair
        p12[q] = id[q] - 4095;
        float lv = blocked[p12[q] << 7];
        bool r = s[q] > lv;
        s[q] = r ? s[q] - lv : s[q];
        k[q] = r ? 1 : 0;
    }
    #pragma unroll
    for (int d = 0; d < 5; ++d) {               // levels 14..18, same 512 B record
        #pragma unroll
        for (int q = 0; q < 4; ++q) {
            int left = 2 * k[q] + 2;
            float lv = blocked[(p12[q] << 7) + left];
            bool r = s[q] > lv;
            s[q] = r ? s[q] - lv : s[q];
            k[q] = r ? left + 1 : left;
        }
    }

    #pragma unroll
    for (int q = 0; q < 4; ++q) {               // levels 19,20 + leaf in-register
        int p = (p12[q] << 6) + (k[q] - 62);    // level-18 position
        const float4* pp = (const float4*)prio + 2 * (size_t)p;
        float4 x = pp[0], y = pp[1];            // leaves 8p..8p+7
        float l19 = (x.x + x.y) + (x.z + x.w);
        bool r1 = s[q] > l19;
        float ss = r1 ? s[q] - l19 : s[q];
        float l20 = r1 ? (y.x + y.y) : (x.x + x.y);
        bool r2 = ss > l20;
        ss = r2 ? ss - l20 : ss;
        float leaf = r1 ? (r2 ? y.z : y.x) : (r2 ? x.z : x.x);
        bool r3 = ss > leaf;
        out[base + 256 * q] = 8 * p + (r1 ? 4 : 0) + (r2 ? 2 : 0) + (r3 ? 1 : 0);
    }
}

extern "C" void kernel_launch(void* const* d_in, const int* in_sizes, int n_in,
                              void* d_out, int out_size, void* d_ws, size_t ws_size,
                              hipStream_t stream) {
    const float* prio    = (const float*)d_in[0];   // [CAP]
    const float* uniform = (const float*)d_in[1];   // [NSAMP]
    (void)in_sizes; (void)n_in; (void)out_size; (void)ws_size;

    float* tree    = (float*)d_ws;                  // slots 1023..8190 used
    float* blocked = (float*)d_ws + 8192;           // 4096 x 128 floats, 512B-aligned

    build_tree<<<512, 256, 0, stream>>>(prio, tree, blocked);
    sample_kernel<<<NSAMP / 1024, 256, 0, stream>>>(tree, blocked, prio, uniform, (int*)d_out);
}